// Round 2
// baseline (1162.870 us; speedup 1.0000x reference)
//
#include <hip/hip_runtime.h>
#include <cstdint>

typedef unsigned short u16;
using bf16x8 = __attribute__((ext_vector_type(8))) __bf16;
using f32x4  = __attribute__((ext_vector_type(4))) float;

#define MFMA(a, b, c) __builtin_amdgcn_mfma_f32_16x16x32_bf16((a), (b), (c), 0, 0, 0)

__device__ __forceinline__ float b2f(u16 u) {
    union { unsigned int i; float f; } x; x.i = ((unsigned int)u) << 16; return x.f;
}
__device__ __forceinline__ u16 f2b(float f) {
    union { float f; unsigned int i; } x; x.f = f;
    unsigned int r = x.i + 0x7FFFu + ((x.i >> 16) & 1u);
    return (u16)(r >> 16);
}

// ---------------------------------------------------------------------------
// QKV projection: per (b,h): q/k/v[b,h] = x[b] @ w[h] + bias[h]
// X fp32 [B*S,1024]; W* fp32 [16,1024,64]; out bf16 [B,H,S,64]
// grid (B*H=64, S/128=16), block 256
// ---------------------------------------------------------------------------
__global__ __launch_bounds__(256) void qkv_kernel(
    const float* __restrict__ X,
    const float* __restrict__ Wq, const float* __restrict__ Bq,
    const float* __restrict__ Wk, const float* __restrict__ Bk,
    const float* __restrict__ Wv, const float* __restrict__ Bv,
    u16* __restrict__ Qo, u16* __restrict__ Ko, u16* __restrict__ Vo)
{
    const int bh = blockIdx.x;
    const int b = bh >> 4, h = bh & 15;
    const int m0 = blockIdx.y * 128;
    const int tid = threadIdx.x;
    const int lane = tid & 63, w = tid >> 6;
    const int g = lane >> 4, ln = lane & 15;

    __shared__ __align__(16) u16 As[128][72];
    __shared__ __align__(16) u16 Bs[3][64][72];   // transposed [n][k]

    const float* Wmats[3] = {Wq + h * 65536, Wk + h * 65536, Wv + h * 65536};

    f32x4 acc[2][12];
    #pragma unroll
    for (int i = 0; i < 2; ++i)
        #pragma unroll
        for (int j = 0; j < 12; ++j) acc[i][j] = (f32x4){0.f, 0.f, 0.f, 0.f};

    const float* Xrow = X + (size_t)(b * 2048 + m0) * 1024;

    for (int k0 = 0; k0 < 1024; k0 += 64) {
        #pragma unroll
        for (int it = 0; it < 8; ++it) {
            int vI = tid + it * 256;               // 0..2047
            int row = vI >> 4, col = (vI & 15) * 4;
            float4 f = *reinterpret_cast<const float4*>(&Xrow[(size_t)row * 1024 + k0 + col]);
            ushort4 s = {f2b(f.x), f2b(f.y), f2b(f.z), f2b(f.w)};
            *reinterpret_cast<ushort4*>(&As[row][col]) = s;
        }
        #pragma unroll
        for (int m = 0; m < 3; ++m) {
            #pragma unroll
            for (int it = 0; it < 4; ++it) {
                int vI = tid + it * 256;           // 0..1023
                int kr = vI >> 4, nc = (vI & 15) * 4;
                float4 f = *reinterpret_cast<const float4*>(
                    &Wmats[m][(size_t)(k0 + kr) * 64 + nc]);
                Bs[m][nc + 0][kr] = f2b(f.x);
                Bs[m][nc + 1][kr] = f2b(f.y);
                Bs[m][nc + 2][kr] = f2b(f.z);
                Bs[m][nc + 3][kr] = f2b(f.w);
            }
        }
        __syncthreads();
        #pragma unroll
        for (int kk = 0; kk < 2; ++kk) {
            bf16x8 a[2];
            a[0] = *(const bf16x8*)&As[w * 32 + ln][kk * 32 + g * 8];
            a[1] = *(const bf16x8*)&As[w * 32 + 16 + ln][kk * 32 + g * 8];
            #pragma unroll
            for (int m = 0; m < 3; ++m)
                #pragma unroll
                for (int j = 0; j < 4; ++j) {
                    bf16x8 bb = *(const bf16x8*)&Bs[m][j * 16 + ln][kk * 32 + g * 8];
                    acc[0][m * 4 + j] = MFMA(a[0], bb, acc[0][m * 4 + j]);
                    acc[1][m * 4 + j] = MFMA(a[1], bb, acc[1][m * 4 + j]);
                }
        }
        __syncthreads();
    }

    u16* outs[3] = {Qo, Ko, Vo};
    const float* biases[3] = {Bq, Bk, Bv};
    const size_t base = ((size_t)bh * 2048 + m0) * 64;
    #pragma unroll
    for (int m = 0; m < 3; ++m)
        #pragma unroll
        for (int i = 0; i < 2; ++i)
            #pragma unroll
            for (int j = 0; j < 4; ++j) {
                float bv = biases[m][h * 64 + j * 16 + ln];
                #pragma unroll
                for (int r = 0; r < 4; ++r) {
                    int row = w * 32 + i * 16 + g * 4 + r;
                    outs[m][base + (size_t)row * 64 + j * 16 + ln] =
                        f2b(acc[i][m * 4 + j][r] + bv);
                }
            }
}

// ---------------------------------------------------------------------------
// Flash attention (all bf16 in/out, internal buffers): block per (b,h,128 q)
// O written directly in concat layout [B,S,1024] at column h*64.
// ---------------------------------------------------------------------------
__global__ __launch_bounds__(256) void attn_kernel(
    const u16* __restrict__ Qm, const u16* __restrict__ Km,
    const u16* __restrict__ Vm, u16* __restrict__ O)
{
    const int bh = blockIdx.x, b = bh >> 4, h = bh & 15;
    const int q0 = blockIdx.y * 128;
    const int tid = threadIdx.x;
    const int lane = tid & 63, w = tid >> 6;
    const int g = lane >> 4, ln = lane & 15;

    __shared__ __align__(16) u16 Qs[128][72];
    __shared__ __align__(16) u16 Ks[64][72];
    __shared__ __align__(16) u16 Vts[64][72];
    __shared__ __align__(16) u16 Ps[128][72];

    const size_t hb = (size_t)bh * 2048 * 64;

    #pragma unroll
    for (int it = 0; it < 4; ++it) {
        int vI = tid + it * 256;
        int row = vI >> 3, col = (vI & 7) * 8;
        *reinterpret_cast<uint4*>(&Qs[row][col]) =
            *reinterpret_cast<const uint4*>(&Qm[hb + (size_t)(q0 + row) * 64 + col]);
    }

    f32x4 oacc[2][4];
    float mrun[2][4], lrun[2][4];
    #pragma unroll
    for (int i = 0; i < 2; ++i)
        #pragma unroll
        for (int n = 0; n < 4; ++n) oacc[i][n] = (f32x4){0.f, 0.f, 0.f, 0.f};
    #pragma unroll
    for (int i = 0; i < 2; ++i)
        #pragma unroll
        for (int r = 0; r < 4; ++r) { mrun[i][r] = -1e30f; lrun[i][r] = 0.f; }

    for (int t0 = 0; t0 < 2048; t0 += 64) {
        __syncthreads();   // prev PV reads done before overwriting Ks/Vts
        #pragma unroll
        for (int it = 0; it < 2; ++it) {
            int vI = tid + it * 256;
            int row = vI >> 3, col = (vI & 7) * 8;
            *reinterpret_cast<uint4*>(&Ks[row][col]) =
                *reinterpret_cast<const uint4*>(&Km[hb + (size_t)(t0 + row) * 64 + col]);
            uint4 t = *reinterpret_cast<const uint4*>(&Vm[hb + (size_t)(t0 + row) * 64 + col]);
            const u16* tv = reinterpret_cast<const u16*>(&t);
            #pragma unroll
            for (int j = 0; j < 8; ++j) Vts[col + j][row] = tv[j];
        }
        __syncthreads();

        // S = Q K^T
        f32x4 sacc[2][4];
        #pragma unroll
        for (int i = 0; i < 2; ++i)
            #pragma unroll
            for (int j = 0; j < 4; ++j) sacc[i][j] = (f32x4){0.f, 0.f, 0.f, 0.f};
        #pragma unroll
        for (int kk = 0; kk < 2; ++kk) {
            bf16x8 a[2];
            a[0] = *(const bf16x8*)&Qs[w * 32 + ln][kk * 32 + g * 8];
            a[1] = *(const bf16x8*)&Qs[w * 32 + 16 + ln][kk * 32 + g * 8];
            #pragma unroll
            for (int j = 0; j < 4; ++j) {
                bf16x8 bb = *(const bf16x8*)&Ks[j * 16 + ln][kk * 32 + g * 8];
                sacc[0][j] = MFMA(a[0], bb, sacc[0][j]);
                sacc[1][j] = MFMA(a[1], bb, sacc[1][j]);
            }
        }

        // online softmax (scale 1/8 folded in)
        #pragma unroll
        for (int i = 0; i < 2; ++i)
            #pragma unroll
            for (int r = 0; r < 4; ++r) {
                float tmax = sacc[i][0][r];
                #pragma unroll
                for (int j = 1; j < 4; ++j) tmax = fmaxf(tmax, sacc[i][j][r]);
                #pragma unroll
                for (int mm = 1; mm < 16; mm <<= 1)
                    tmax = fmaxf(tmax, __shfl_xor(tmax, mm));
                tmax *= 0.125f;
                float mn = fmaxf(mrun[i][r], tmax);
                float al = __expf(mrun[i][r] - mn);
                float ps = 0.f;
                #pragma unroll
                for (int j = 0; j < 4; ++j) {
                    float p = __expf(fmaf(sacc[i][j][r], 0.125f, -mn));
                    sacc[i][j][r] = p;
                    ps += p;
                }
                #pragma unroll
                for (int mm = 1; mm < 16; mm <<= 1)
                    ps += __shfl_xor(ps, mm);
                lrun[i][r] = lrun[i][r] * al + ps;
                mrun[i][r] = mn;
                #pragma unroll
                for (int n = 0; n < 4; ++n) oacc[i][n][r] *= al;
                #pragma unroll
                for (int j = 0; j < 4; ++j)
                    Ps[w * 32 + i * 16 + g * 4 + r][j * 16 + ln] = f2b(sacc[i][j][r]);
            }
        __syncthreads();

        // O += P V
        #pragma unroll
        for (int kk = 0; kk < 2; ++kk) {
            bf16x8 a[2];
            a[0] = *(const bf16x8*)&Ps[w * 32 + ln][kk * 32 + g * 8];
            a[1] = *(const bf16x8*)&Ps[w * 32 + 16 + ln][kk * 32 + g * 8];
            #pragma unroll
            for (int n = 0; n < 4; ++n) {
                bf16x8 bb = *(const bf16x8*)&Vts[n * 16 + ln][kk * 32 + g * 8];
                oacc[0][n] = MFMA(a[0], bb, oacc[0][n]);
                oacc[1][n] = MFMA(a[1], bb, oacc[1][n]);
            }
        }
    }

    #pragma unroll
    for (int i = 0; i < 2; ++i)
        #pragma unroll
        for (int n = 0; n < 4; ++n)
            #pragma unroll
            for (int r = 0; r < 4; ++r) {
                int row = q0 + w * 32 + i * 16 + g * 4 + r;
                float v = oacc[i][n][r] / lrun[i][r];
                O[((size_t)(b * 2048 + row)) * 1024 + h * 64 + n * 16 + ln] = f2b(v);
            }
}

// ---------------------------------------------------------------------------
// out[row] = Src[row] + LayerNorm(T[row]) * g + b    (row = 1024 elems)
// T bf16.  Src fp32 or bf16.  Out fp32 or bf16.
// ---------------------------------------------------------------------------
template <int SRC_F32, int OUT_F32>
__global__ __launch_bounds__(256) void ln_add_kernel(
    const u16* __restrict__ T, const void* __restrict__ SrcV,
    const float* __restrict__ G, const float* __restrict__ Bt,
    void* __restrict__ OutV)
{
    const int row = blockIdx.x;
    const int tid = threadIdx.x;
    __shared__ float red[8];

    const size_t rb = (size_t)row * 1024;
    ushort4 tv = *reinterpret_cast<const ushort4*>(&T[rb + tid * 4]);
    float v0 = b2f(tv.x), v1 = b2f(tv.y), v2 = b2f(tv.z), v3 = b2f(tv.w);
    float s = v0 + v1 + v2 + v3;
    float sq = v0 * v0 + v1 * v1 + v2 * v2 + v3 * v3;
    #pragma unroll
    for (int mm = 1; mm < 64; mm <<= 1) {
        s += __shfl_xor(s, mm);
        sq += __shfl_xor(sq, mm);
    }
    if ((tid & 63) == 0) { red[tid >> 6] = s; red[4 + (tid >> 6)] = sq; }
    __syncthreads();
    s = red[0] + red[1] + red[2] + red[3];
    sq = red[4] + red[5] + red[6] + red[7];
    float mu = s * (1.f / 1024.f);
    float var = sq * (1.f / 1024.f) - mu * mu;
    float rs = rsqrtf(var + 1e-5f);

    float s0, s1, s2, s3;
    if (SRC_F32) {
        float4 sv = *reinterpret_cast<const float4*>((const float*)SrcV + rb + tid * 4);
        s0 = sv.x; s1 = sv.y; s2 = sv.z; s3 = sv.w;
    } else {
        ushort4 sv = *reinterpret_cast<const ushort4*>((const u16*)SrcV + rb + tid * 4);
        s0 = b2f(sv.x); s1 = b2f(sv.y); s2 = b2f(sv.z); s3 = b2f(sv.w);
    }
    float4 gv = *reinterpret_cast<const float4*>(&G[tid * 4]);
    float4 bv = *reinterpret_cast<const float4*>(&Bt[tid * 4]);
    float o0 = s0 + (v0 - mu) * rs * gv.x + bv.x;
    float o1 = s1 + (v1 - mu) * rs * gv.y + bv.y;
    float o2 = s2 + (v2 - mu) * rs * gv.z + bv.z;
    float o3 = s3 + (v3 - mu) * rs * gv.w + bv.w;
    if (OUT_F32) {
        float4 ov = {o0, o1, o2, o3};
        *reinterpret_cast<float4*>((float*)OutV + rb + tid * 4) = ov;
    } else {
        ushort4 ov = {f2b(o0), f2b(o1), f2b(o2), f2b(o3)};
        *reinterpret_cast<ushort4*>((u16*)OutV + rb + tid * 4) = ov;
    }
}

// ---------------------------------------------------------------------------
// C = act(A @ B + bias): A [M,K] bf16 row-major, B [K,N] FP32 row-major.
// 128x128 tile, BK=64, 4 waves 2x2. Out bf16.
// ---------------------------------------------------------------------------
template <int RELU>
__global__ __launch_bounds__(256) void gemm_kernel(
    const u16* __restrict__ A, const float* __restrict__ Bm,
    const float* __restrict__ bias, u16* __restrict__ C,
    int M, int N, int K)
{
    __shared__ __align__(16) u16 As[128][72];
    __shared__ __align__(16) u16 Bs[128][72];   // transposed [n][k]
    const int m0 = blockIdx.x * 128, n0 = blockIdx.y * 128;
    const int tid = threadIdx.x, lane = tid & 63, w = tid >> 6;
    const int wr = w >> 1, wc = w & 1;
    const int g = lane >> 4, ln = lane & 15;

    f32x4 acc[4][4];
    #pragma unroll
    for (int i = 0; i < 4; ++i)
        #pragma unroll
        for (int j = 0; j < 4; ++j) acc[i][j] = (f32x4){0.f, 0.f, 0.f, 0.f};

    for (int k0 = 0; k0 < K; k0 += 64) {
        #pragma unroll
        for (int it = 0; it < 4; ++it) {
            int vI = tid + it * 256;
            int row = vI >> 3, col = (vI & 7) * 8;
            *reinterpret_cast<uint4*>(&As[row][col]) =
                *reinterpret_cast<const uint4*>(&A[(size_t)(m0 + row) * K + k0 + col]);
        }
        #pragma unroll
        for (int it = 0; it < 8; ++it) {
            int vI = tid + it * 256;               // 0..2047: 64 k x 32 n-vec4
            int kr = vI >> 5, nc = (vI & 31) * 4;
            float4 f = *reinterpret_cast<const float4*>(&Bm[(size_t)(k0 + kr) * N + n0 + nc]);
            Bs[nc + 0][kr] = f2b(f.x);
            Bs[nc + 1][kr] = f2b(f.y);
            Bs[nc + 2][kr] = f2b(f.z);
            Bs[nc + 3][kr] = f2b(f.w);
        }
        __syncthreads();
        #pragma unroll
        for (int kk = 0; kk < 2; ++kk) {
            bf16x8 a[4], bfr[4];
            #pragma unroll
            for (int i = 0; i < 4; ++i)
                a[i] = *(const bf16x8*)&As[wr * 64 + i * 16 + ln][kk * 32 + g * 8];
            #pragma unroll
            for (int j = 0; j < 4; ++j)
                bfr[j] = *(const bf16x8*)&Bs[wc * 64 + j * 16 + ln][kk * 32 + g * 8];
            #pragma unroll
            for (int i = 0; i < 4; ++i)
                #pragma unroll
                for (int j = 0; j < 4; ++j)
                    acc[i][j] = MFMA(a[i], bfr[j], acc[i][j]);
        }
        __syncthreads();
    }

    #pragma unroll
    for (int i = 0; i < 4; ++i)
        #pragma unroll
        for (int j = 0; j < 4; ++j) {
            int col = n0 + wc * 64 + j * 16 + ln;
            float bv = bias[col];
            #pragma unroll
            for (int r = 0; r < 4; ++r) {
                int row = m0 + wr * 64 + i * 16 + g * 4 + r;
                float v = acc[i][j][r] + bv;
                if (RELU) v = fmaxf(v, 0.f);
                C[(size_t)row * N + col] = f2b(v);
            }
        }
}

// ---------------------------------------------------------------------------
extern "C" void kernel_launch(void* const* d_in, const int* in_sizes, int n_in,
                              void* d_out, int out_size, void* d_ws, size_t ws_size,
                              hipStream_t stream)
{
    const float* X   = (const float*)d_in[0];
    const float* Wq  = (const float*)d_in[1];
    const float* Bq  = (const float*)d_in[2];
    const float* Wk  = (const float*)d_in[3];
    const float* Bk  = (const float*)d_in[4];
    const float* Wv  = (const float*)d_in[5];
    const float* Bv  = (const float*)d_in[6];
    const float* g1  = (const float*)d_in[7];
    const float* b1  = (const float*)d_in[8];
    const float* W1  = (const float*)d_in[9];
    const float* B1  = (const float*)d_in[10];
    const float* W2  = (const float*)d_in[11];
    const float* B2  = (const float*)d_in[12];
    const float* g2  = (const float*)d_in[13];
    const float* b2  = (const float*)d_in[14];
    float* out = (float*)d_out;

    char* ws = (char*)d_ws;
    const size_t MiB = 1048576;
    u16* q    = (u16*)(ws);                // 16MiB (aliased by hid later)
    u16* k    = (u16*)(ws + 16 * MiB);     // 16MiB
    u16* v    = (u16*)(ws + 32 * MiB);     // 16MiB
    u16* attn = (u16*)(ws + 48 * MiB);     // 16MiB
    u16* hid  = (u16*)(ws);                // 64MiB, reuses q/k/v/attn (dead)
    u16* res1 = (u16*)(ws + 64 * MiB);     // 16MiB
    u16* ff   = (u16*)(ws + 80 * MiB);     // 16MiB  -> total 96MiB

    qkv_kernel<<<dim3(64, 16), 256, 0, stream>>>(X, Wq, Bq, Wk, Bk, Wv, Bv, q, k, v);
    attn_kernel<<<dim3(64, 16), 256, 0, stream>>>(q, k, v, attn);
    ln_add_kernel<1, 0><<<8192, 256, 0, stream>>>(attn, X, g1, b1, res1);
    gemm_kernel<1><<<dim3(64, 32), 256, 0, stream>>>(res1, W1, B1, hid, 8192, 4096, 1024);
    gemm_kernel<0><<<dim3(64, 8), 256, 0, stream>>>(hid, W2, B2, ff, 8192, 1024, 4096);
    ln_add_kernel<0, 1><<<8192, 256, 0, stream>>>(ff, res1, g2, b2, out);
}

// Round 3
// 675.587 us; speedup vs baseline: 1.7213x; 1.7213x over previous
//
#include <hip/hip_runtime.h>
#include <cstdint>

typedef unsigned short u16;
using bf16x8 = __attribute__((ext_vector_type(8))) __bf16;
using f32x4  = __attribute__((ext_vector_type(4))) float;

#define MFMA(a, b, c) __builtin_amdgcn_mfma_f32_16x16x32_bf16((a), (b), (c), 0, 0, 0)

__device__ __forceinline__ float b2f(u16 u) {
    union { unsigned int i; float f; } x; x.i = ((unsigned int)u) << 16; return x.f;
}
__device__ __forceinline__ u16 f2b(float f) {
    union { float f; unsigned int i; } x; x.f = f;
    unsigned int r = x.i + 0x7FFFu + ((x.i >> 16) & 1u);
    return (u16)(r >> 16);
}

// async global -> LDS, 16B per lane. LDS dest = wave-uniform base + lane*16.
__device__ __forceinline__ void gload16(const u16* g, u16* l) {
    __builtin_amdgcn_global_load_lds(
        (const __attribute__((address_space(1))) void*)g,
        (__attribute__((address_space(3))) void*)l, 16, 0, 0);
}

// ---------------------------------------------------------------------------
// X fp32 -> bf16 (contiguous, 8 elems/thread)
// ---------------------------------------------------------------------------
__global__ __launch_bounds__(256) void xcvt_kernel(const float* __restrict__ X,
                                                   u16* __restrict__ Xb)
{
    size_t i = ((size_t)blockIdx.x * 256 + threadIdx.x) * 8;
    float4 a = *reinterpret_cast<const float4*>(&X[i]);
    float4 b = *reinterpret_cast<const float4*>(&X[i + 4]);
    ushort4 lo = {f2b(a.x), f2b(a.y), f2b(a.z), f2b(a.w)};
    ushort4 hi = {f2b(b.x), f2b(b.y), f2b(b.z), f2b(b.w)};
    *reinterpret_cast<ushort4*>(&Xb[i]) = lo;
    *reinterpret_cast<ushort4*>(&Xb[i + 4]) = hi;
}

// ---------------------------------------------------------------------------
// W [K,N] fp32 -> Wt [N,K] bf16   (64x64 tiles via LDS)
// ---------------------------------------------------------------------------
__global__ __launch_bounds__(256) void wT_kernel(const float* __restrict__ W,
                                                 u16* __restrict__ Wt, int K, int N)
{
    __shared__ __align__(16) u16 Ts[64][72];   // 144B row stride = 9x16B, aligned
    const int k0 = blockIdx.x * 64, n0 = blockIdx.y * 64;
    const int tid = threadIdx.x;
    #pragma unroll
    for (int it = 0; it < 4; ++it) {
        int vI = tid + it * 256;               // 64 k x 16 n-vec4
        int kr = vI >> 4, nc = (vI & 15) * 4;
        float4 f = *reinterpret_cast<const float4*>(&W[(size_t)(k0 + kr) * N + n0 + nc]);
        Ts[nc + 0][kr] = f2b(f.x);
        Ts[nc + 1][kr] = f2b(f.y);
        Ts[nc + 2][kr] = f2b(f.z);
        Ts[nc + 3][kr] = f2b(f.w);
    }
    __syncthreads();
    #pragma unroll
    for (int it = 0; it < 2; ++it) {
        int vI = tid + it * 256;               // 64 n x 8 k-vec8
        int nr = vI >> 3, kc = (vI & 7) * 8;
        *reinterpret_cast<uint4*>(&Wt[(size_t)(n0 + nr) * K + k0 + kc]) =
            *reinterpret_cast<uint4*>(&Ts[nr][kc]);
    }
}

// ---------------------------------------------------------------------------
// Wq/Wk/Wv [16,1024,64] fp32 -> Wcat_t [3072,1024] bf16, row = m*1024+h*64+d
// grid (16 kTiles, 16 heads, 3 matrices)
// ---------------------------------------------------------------------------
__global__ __launch_bounds__(256) void wqkvT_kernel(
    const float* __restrict__ Wq, const float* __restrict__ Wk,
    const float* __restrict__ Wv, u16* __restrict__ Wt)
{
    __shared__ __align__(16) u16 Ts[64][72];
    const int k0 = blockIdx.x * 64, h = blockIdx.y, m = blockIdx.z;
    const float* W = (m == 0 ? Wq : (m == 1 ? Wk : Wv)) + (size_t)h * 65536;
    const int tid = threadIdx.x;
    #pragma unroll
    for (int it = 0; it < 4; ++it) {
        int vI = tid + it * 256;               // 64 k x 16 d-vec4
        int kr = vI >> 4, dc = (vI & 15) * 4;
        float4 f = *reinterpret_cast<const float4*>(&W[(size_t)(k0 + kr) * 64 + dc]);
        Ts[dc + 0][kr] = f2b(f.x);
        Ts[dc + 1][kr] = f2b(f.y);
        Ts[dc + 2][kr] = f2b(f.z);
        Ts[dc + 3][kr] = f2b(f.w);
    }
    __syncthreads();
    #pragma unroll
    for (int it = 0; it < 2; ++it) {
        int vI = tid + it * 256;               // 64 d x 8 k-vec8
        int dr = vI >> 3, kc = (vI & 7) * 8;
        *reinterpret_cast<uint4*>(
            &Wt[((size_t)(m * 1024 + h * 64 + dr)) * 1024 + k0 + kc]) =
            *reinterpret_cast<uint4*>(&Ts[dr][kc]);
    }
}

__global__ __launch_bounds__(256) void biascat_kernel(
    const float* __restrict__ Bq, const float* __restrict__ Bk,
    const float* __restrict__ Bv, float* __restrict__ out)
{
    int i = blockIdx.x * 256 + threadIdx.x;    // 0..3071
    const float* B = (i < 1024 ? Bq : (i < 2048 ? Bk : Bv));
    out[i] = B[i & 1023];
}

// ---------------------------------------------------------------------------
// C = act(A @ Bt^T + bias): A [M,K] bf16, Bt [N,K] bf16 (both row-major along K).
// 128x128 tile, BK=64, 4 waves 2x2. global_load_lds staging, linear LDS.
// ---------------------------------------------------------------------------
template <int RELU>
__global__ __launch_bounds__(256) void gemm_bt(
    const u16* __restrict__ A, const u16* __restrict__ Bt,
    const float* __restrict__ bias, u16* __restrict__ C,
    int M, int N, int K)
{
    __shared__ __align__(16) u16 As[128 * 64];
    __shared__ __align__(16) u16 Bs[128 * 64];
    const int m0 = blockIdx.x * 128, n0 = blockIdx.y * 128;
    const int tid = threadIdx.x, lane = tid & 63, w = tid >> 6;
    const int wr = w >> 1, wc = w & 1;
    const int g = lane >> 4, ln = lane & 15;
    const int srow = lane >> 3, scol = (lane & 7) * 8;

    f32x4 acc[4][4];
    #pragma unroll
    for (int i = 0; i < 4; ++i)
        #pragma unroll
        for (int j = 0; j < 4; ++j) acc[i][j] = (f32x4){0.f, 0.f, 0.f, 0.f};

    const u16* Abase = A + (size_t)m0 * K;
    const u16* Bbase = Bt + (size_t)n0 * K;

    for (int k0 = 0; k0 < K; k0 += 64) {
        #pragma unroll
        for (int c = 0; c < 4; ++c) {
            int chunk = w * 4 + c;             // 0..15, wave-uniform
            int row = chunk * 8 + srow;
            gload16(&Abase[(size_t)row * K + k0 + scol], (u16*)As + chunk * 512);
            gload16(&Bbase[(size_t)row * K + k0 + scol], (u16*)Bs + chunk * 512);
        }
        __syncthreads();                        // drains vmcnt before reads
        #pragma unroll
        for (int kk = 0; kk < 2; ++kk) {
            bf16x8 a[4], b[4];
            #pragma unroll
            for (int i = 0; i < 4; ++i)
                a[i] = *(const bf16x8*)&As[(wr * 64 + i * 16 + ln) * 64 + kk * 32 + g * 8];
            #pragma unroll
            for (int j = 0; j < 4; ++j)
                b[j] = *(const bf16x8*)&Bs[(wc * 64 + j * 16 + ln) * 64 + kk * 32 + g * 8];
            #pragma unroll
            for (int i = 0; i < 4; ++i)
                #pragma unroll
                for (int j = 0; j < 4; ++j)
                    acc[i][j] = MFMA(a[i], b[j], acc[i][j]);
        }
        __syncthreads();
    }

    #pragma unroll
    for (int j = 0; j < 4; ++j) {
        int col = n0 + wc * 64 + j * 16 + ln;
        float bv = bias[col];
        #pragma unroll
        for (int i = 0; i < 4; ++i)
            #pragma unroll
            for (int r = 0; r < 4; ++r) {
                int row = m0 + wr * 64 + i * 16 + g * 4 + r;
                float v = acc[i][j][r] + bv;
                if (RELU) v = fmaxf(v, 0.f);
                C[(size_t)row * N + col] = f2b(v);
            }
    }
}

// ---------------------------------------------------------------------------
// Flash attention over fused qkv buffer [8192, 3072] bf16
// (Q at col h*64, K at 1024+h*64, V at 2048+h*64; row stride 3072)
// O written in concat layout [B,S,1024] at column h*64.
// ---------------------------------------------------------------------------
__global__ __launch_bounds__(256) void attn_kernel(
    const u16* __restrict__ QKV, u16* __restrict__ O)
{
    const int bh = blockIdx.x, b = bh >> 4, h = bh & 15;
    const int q0 = blockIdx.y * 128;
    const int tid = threadIdx.x;
    const int lane = tid & 63, w = tid >> 6;
    const int g = lane >> 4, ln = lane & 15;

    __shared__ __align__(16) u16 Qs[128][72];
    __shared__ __align__(16) u16 Ks[64][72];
    __shared__ __align__(16) u16 Vts[64][72];
    __shared__ __align__(16) u16 Ps[128][72];

    const u16* Qp = QKV + (size_t)b * 2048 * 3072 + h * 64;
    const u16* Kp = Qp + 1024;
    const u16* Vp = Qp + 2048;

    #pragma unroll
    for (int it = 0; it < 4; ++it) {
        int vI = tid + it * 256;
        int row = vI >> 3, col = (vI & 7) * 8;
        *reinterpret_cast<uint4*>(&Qs[row][col]) =
            *reinterpret_cast<const uint4*>(&Qp[(size_t)(q0 + row) * 3072 + col]);
    }

    f32x4 oacc[2][4];
    float mrun[2][4], lrun[2][4];
    #pragma unroll
    for (int i = 0; i < 2; ++i)
        #pragma unroll
        for (int n = 0; n < 4; ++n) oacc[i][n] = (f32x4){0.f, 0.f, 0.f, 0.f};
    #pragma unroll
    for (int i = 0; i < 2; ++i)
        #pragma unroll
        for (int r = 0; r < 4; ++r) { mrun[i][r] = -1e30f; lrun[i][r] = 0.f; }

    for (int t0 = 0; t0 < 2048; t0 += 64) {
        __syncthreads();   // prev PV reads done before overwriting Ks/Vts
        #pragma unroll
        for (int it = 0; it < 2; ++it) {
            int vI = tid + it * 256;
            int row = vI >> 3, col = (vI & 7) * 8;
            *reinterpret_cast<uint4*>(&Ks[row][col]) =
                *reinterpret_cast<const uint4*>(&Kp[(size_t)(t0 + row) * 3072 + col]);
            uint4 t = *reinterpret_cast<const uint4*>(&Vp[(size_t)(t0 + row) * 3072 + col]);
            const u16* tv = reinterpret_cast<const u16*>(&t);
            #pragma unroll
            for (int j = 0; j < 8; ++j) Vts[col + j][row] = tv[j];
        }
        __syncthreads();

        // S = Q K^T
        f32x4 sacc[2][4];
        #pragma unroll
        for (int i = 0; i < 2; ++i)
            #pragma unroll
            for (int j = 0; j < 4; ++j) sacc[i][j] = (f32x4){0.f, 0.f, 0.f, 0.f};
        #pragma unroll
        for (int kk = 0; kk < 2; ++kk) {
            bf16x8 a[2];
            a[0] = *(const bf16x8*)&Qs[w * 32 + ln][kk * 32 + g * 8];
            a[1] = *(const bf16x8*)&Qs[w * 32 + 16 + ln][kk * 32 + g * 8];
            #pragma unroll
            for (int j = 0; j < 4; ++j) {
                bf16x8 bb = *(const bf16x8*)&Ks[j * 16 + ln][kk * 32 + g * 8];
                sacc[0][j] = MFMA(a[0], bb, sacc[0][j]);
                sacc[1][j] = MFMA(a[1], bb, sacc[1][j]);
            }
        }

        // online softmax (scale 1/8 folded in)
        #pragma unroll
        for (int i = 0; i < 2; ++i)
            #pragma unroll
            for (int r = 0; r < 4; ++r) {
                float tmax = sacc[i][0][r];
                #pragma unroll
                for (int j = 1; j < 4; ++j) tmax = fmaxf(tmax, sacc[i][j][r]);
                #pragma unroll
                for (int mm = 1; mm < 16; mm <<= 1)
                    tmax = fmaxf(tmax, __shfl_xor(tmax, mm));
                tmax *= 0.125f;
                float mn = fmaxf(mrun[i][r], tmax);
                float al = __expf(mrun[i][r] - mn);
                float ps = 0.f;
                #pragma unroll
                for (int j = 0; j < 4; ++j) {
                    float p = __expf(fmaf(sacc[i][j][r], 0.125f, -mn));
                    sacc[i][j][r] = p;
                    ps += p;
                }
                #pragma unroll
                for (int mm = 1; mm < 16; mm <<= 1)
                    ps += __shfl_xor(ps, mm);
                lrun[i][r] = lrun[i][r] * al + ps;
                mrun[i][r] = mn;
                #pragma unroll
                for (int n = 0; n < 4; ++n) oacc[i][n][r] *= al;
                #pragma unroll
                for (int j = 0; j < 4; ++j)
                    Ps[w * 32 + i * 16 + g * 4 + r][j * 16 + ln] = f2b(sacc[i][j][r]);
            }
        __syncthreads();

        // O += P V
        #pragma unroll
        for (int kk = 0; kk < 2; ++kk) {
            bf16x8 a[2];
            a[0] = *(const bf16x8*)&Ps[w * 32 + ln][kk * 32 + g * 8];
            a[1] = *(const bf16x8*)&Ps[w * 32 + 16 + ln][kk * 32 + g * 8];
            #pragma unroll
            for (int n = 0; n < 4; ++n) {
                bf16x8 bb = *(const bf16x8*)&Vts[n * 16 + ln][kk * 32 + g * 8];
                oacc[0][n] = MFMA(a[0], bb, oacc[0][n]);
                oacc[1][n] = MFMA(a[1], bb, oacc[1][n]);
            }
        }
    }

    #pragma unroll
    for (int i = 0; i < 2; ++i)
        #pragma unroll
        for (int n = 0; n < 4; ++n)
            #pragma unroll
            for (int r = 0; r < 4; ++r) {
                int row = q0 + w * 32 + i * 16 + g * 4 + r;
                float v = oacc[i][n][r] / lrun[i][r];
                O[((size_t)(b * 2048 + row)) * 1024 + h * 64 + n * 16 + ln] = f2b(v);
            }
}

// ---------------------------------------------------------------------------
// out[row] = Src[row] + LayerNorm(T[row]) * g + b    (row = 1024 elems)
// ---------------------------------------------------------------------------
template <int SRC_F32, int OUT_F32>
__global__ __launch_bounds__(256) void ln_add_kernel(
    const u16* __restrict__ T, const void* __restrict__ SrcV,
    const float* __restrict__ G, const float* __restrict__ Bt,
    void* __restrict__ OutV)
{
    const int row = blockIdx.x;
    const int tid = threadIdx.x;
    __shared__ float red[8];

    const size_t rb = (size_t)row * 1024;
    ushort4 tv = *reinterpret_cast<const ushort4*>(&T[rb + tid * 4]);
    float v0 = b2f(tv.x), v1 = b2f(tv.y), v2 = b2f(tv.z), v3 = b2f(tv.w);
    float s = v0 + v1 + v2 + v3;
    float sq = v0 * v0 + v1 * v1 + v2 * v2 + v3 * v3;
    #pragma unroll
    for (int mm = 1; mm < 64; mm <<= 1) {
        s += __shfl_xor(s, mm);
        sq += __shfl_xor(sq, mm);
    }
    if ((tid & 63) == 0) { red[tid >> 6] = s; red[4 + (tid >> 6)] = sq; }
    __syncthreads();
    s = red[0] + red[1] + red[2] + red[3];
    sq = red[4] + red[5] + red[6] + red[7];
    float mu = s * (1.f / 1024.f);
    float var = sq * (1.f / 1024.f) - mu * mu;
    float rs = rsqrtf(var + 1e-5f);

    float s0, s1, s2, s3;
    if (SRC_F32) {
        float4 sv = *reinterpret_cast<const float4*>((const float*)SrcV + rb + tid * 4);
        s0 = sv.x; s1 = sv.y; s2 = sv.z; s3 = sv.w;
    } else {
        ushort4 sv = *reinterpret_cast<const ushort4*>((const u16*)SrcV + rb + tid * 4);
        s0 = b2f(sv.x); s1 = b2f(sv.y); s2 = b2f(sv.z); s3 = b2f(sv.w);
    }
    float4 gv = *reinterpret_cast<const float4*>(&G[tid * 4]);
    float4 bv = *reinterpret_cast<const float4*>(&Bt[tid * 4]);
    float o0 = s0 + (v0 - mu) * rs * gv.x + bv.x;
    float o1 = s1 + (v1 - mu) * rs * gv.y + bv.y;
    float o2 = s2 + (v2 - mu) * rs * gv.z + bv.z;
    float o3 = s3 + (v3 - mu) * rs * gv.w + bv.w;
    if (OUT_F32) {
        float4 ov = {o0, o1, o2, o3};
        *reinterpret_cast<float4*>((float*)OutV + rb + tid * 4) = ov;
    } else {
        ushort4 ov = {f2b(o0), f2b(o1), f2b(o2), f2b(o3)};
        *reinterpret_cast<ushort4*>((u16*)OutV + rb + tid * 4) = ov;
    }
}

// ---------------------------------------------------------------------------
extern "C" void kernel_launch(void* const* d_in, const int* in_sizes, int n_in,
                              void* d_out, int out_size, void* d_ws, size_t ws_size,
                              hipStream_t stream)
{
    const float* X   = (const float*)d_in[0];
    const float* Wq  = (const float*)d_in[1];
    const float* Bq  = (const float*)d_in[2];
    const float* Wk  = (const float*)d_in[3];
    const float* Bk  = (const float*)d_in[4];
    const float* Wv  = (const float*)d_in[5];
    const float* Bv  = (const float*)d_in[6];
    const float* g1  = (const float*)d_in[7];
    const float* b1  = (const float*)d_in[8];
    const float* W1  = (const float*)d_in[9];
    const float* B1  = (const float*)d_in[10];
    const float* W2  = (const float*)d_in[11];
    const float* B2  = (const float*)d_in[12];
    const float* g2  = (const float*)d_in[13];
    const float* b2  = (const float*)d_in[14];
    float* out = (float*)d_out;

    char* ws = (char*)d_ws;
    const size_t MiB = 1048576;
    // lifetimes (96 MiB total):
    u16*   qkv   = (u16*)(ws);              // [8192,3072] 48MiB; dead after attn
    u16*   hid   = (u16*)(ws);              // [4096,4096] 32MiB chunk; after attn
    u16*   ff    = (u16*)(ws + 32 * MiB);   // [8192,1024] 16MiB; after attn
    u16*   Xb    = (u16*)(ws + 48 * MiB);   // 16MiB; dead after qkv gemm
    u16*   attnb = (u16*)(ws + 48 * MiB);   // 16MiB; written after Xb dead
    u16*   wqkvt = (u16*)(ws + 64 * MiB);   // [3072,1024] 6MiB; dead after qkv gemm
    float* bcat  = (float*)(ws + 70 * MiB); // 12KiB; dead after qkv gemm
    u16*   res1  = (u16*)(ws + 64 * MiB);   // 16MiB; written by ln1 (wqkvt dead)
    u16*   w1t   = (u16*)(ws + 80 * MiB);   // [4096,1024] 8MiB
    u16*   w2t   = (u16*)(ws + 88 * MiB);   // [1024,4096] 8MiB

    xcvt_kernel<<<4096, 256, 0, stream>>>(X, Xb);
    wT_kernel<<<dim3(16, 64), 256, 0, stream>>>(W1, w1t, 1024, 4096);
    wT_kernel<<<dim3(64, 16), 256, 0, stream>>>(W2, w2t, 4096, 1024);
    wqkvT_kernel<<<dim3(16, 16, 3), 256, 0, stream>>>(Wq, Wk, Wv, wqkvt);
    biascat_kernel<<<12, 256, 0, stream>>>(Bq, Bk, Bv, bcat);

    gemm_bt<0><<<dim3(64, 24), 256, 0, stream>>>(Xb, wqkvt, bcat, qkv, 8192, 3072, 1024);
    attn_kernel<<<dim3(64, 16), 256, 0, stream>>>(qkv, attnb);
    ln_add_kernel<1, 0><<<8192, 256, 0, stream>>>(attnb, X, g1, b1, res1);

    for (int c = 0; c < 2; ++c) {
        const u16* a1 = res1 + (size_t)c * 4096 * 1024;
        u16* f1 = ff + (size_t)c * 4096 * 1024;
        gemm_bt<1><<<dim3(32, 32), 256, 0, stream>>>(a1, w1t, B1, hid, 4096, 4096, 1024);
        gemm_bt<0><<<dim3(32, 8), 256, 0, stream>>>(hid, w2t, B2, f1, 4096, 1024, 4096);
    }
    ln_add_kernel<0, 1><<<8192, 256, 0, stream>>>(ff, res1, g2, b2, out);
}

// Round 4
// 549.789 us; speedup vs baseline: 2.1151x; 1.2288x over previous
//
#include <hip/hip_runtime.h>
#include <cstdint>
#include <cmath>

typedef unsigned short u16;
using bf16x8 = __attribute__((ext_vector_type(8))) __bf16;
using f32x4  = __attribute__((ext_vector_type(4))) float;

#define MFMA(a, b, c) __builtin_amdgcn_mfma_f32_16x16x32_bf16((a), (b), (c), 0, 0, 0)

__device__ __forceinline__ float b2f(u16 u) {
    union { unsigned int i; float f; } x; x.i = ((unsigned int)u) << 16; return x.f;
}
__device__ __forceinline__ u16 f2b(float f) {
    union { float f; unsigned int i; } x; x.f = f;
    unsigned int r = x.i + 0x7FFFu + ((x.i >> 16) & 1u);
    return (u16)(r >> 16);
}
__device__ __forceinline__ u16 cvtb(float f) {   // compiler-native RNE cvt
    __bf16 h = (__bf16)f;
    return *reinterpret_cast<u16*>(&h);
}

// async global -> LDS, 16B per lane. LDS dest = wave-uniform base + lane*16.
__device__ __forceinline__ void gload16(const u16* g, u16* l) {
    __builtin_amdgcn_global_load_lds(
        (const __attribute__((address_space(1))) void*)g,
        (__attribute__((address_space(3))) void*)l, 16, 0, 0);
}

// ---------------------------------------------------------------------------
// X fp32 -> bf16 (contiguous, 8 elems/thread)
// ---------------------------------------------------------------------------
__global__ __launch_bounds__(256) void xcvt_kernel(const float* __restrict__ X,
                                                   u16* __restrict__ Xb)
{
    size_t i = ((size_t)blockIdx.x * 256 + threadIdx.x) * 8;
    float4 a = *reinterpret_cast<const float4*>(&X[i]);
    float4 b = *reinterpret_cast<const float4*>(&X[i + 4]);
    ushort4 lo = {f2b(a.x), f2b(a.y), f2b(a.z), f2b(a.w)};
    ushort4 hi = {f2b(b.x), f2b(b.y), f2b(b.z), f2b(b.w)};
    *reinterpret_cast<ushort4*>(&Xb[i]) = lo;
    *reinterpret_cast<ushort4*>(&Xb[i + 4]) = hi;
}

// ---------------------------------------------------------------------------
// W [K,N] fp32 -> Wt [N,K] bf16   (64x64 tiles via LDS)
// ---------------------------------------------------------------------------
__global__ __launch_bounds__(256) void wT_kernel(const float* __restrict__ W,
                                                 u16* __restrict__ Wt, int K, int N)
{
    __shared__ __align__(16) u16 Ts[64][72];
    const int k0 = blockIdx.x * 64, n0 = blockIdx.y * 64;
    const int tid = threadIdx.x;
    #pragma unroll
    for (int it = 0; it < 4; ++it) {
        int vI = tid + it * 256;               // 64 k x 16 n-vec4
        int kr = vI >> 4, nc = (vI & 15) * 4;
        float4 f = *reinterpret_cast<const float4*>(&W[(size_t)(k0 + kr) * N + n0 + nc]);
        Ts[nc + 0][kr] = f2b(f.x);
        Ts[nc + 1][kr] = f2b(f.y);
        Ts[nc + 2][kr] = f2b(f.z);
        Ts[nc + 3][kr] = f2b(f.w);
    }
    __syncthreads();
    #pragma unroll
    for (int it = 0; it < 2; ++it) {
        int vI = tid + it * 256;               // 64 n x 8 k-vec8
        int nr = vI >> 3, kc = (vI & 7) * 8;
        *reinterpret_cast<uint4*>(&Wt[(size_t)(n0 + nr) * K + k0 + kc]) =
            *reinterpret_cast<uint4*>(&Ts[nr][kc]);
    }
}

// ---------------------------------------------------------------------------
// Wq/Wk/Wv [16,1024,64] fp32 -> Wcat_t [3072,1024] bf16, row = m*1024+h*64+d
// ---------------------------------------------------------------------------
__global__ __launch_bounds__(256) void wqkvT_kernel(
    const float* __restrict__ Wq, const float* __restrict__ Wk,
    const float* __restrict__ Wv, u16* __restrict__ Wt)
{
    __shared__ __align__(16) u16 Ts[64][72];
    const int k0 = blockIdx.x * 64, h = blockIdx.y, m = blockIdx.z;
    const float* W = (m == 0 ? Wq : (m == 1 ? Wk : Wv)) + (size_t)h * 65536;
    const int tid = threadIdx.x;
    #pragma unroll
    for (int it = 0; it < 4; ++it) {
        int vI = tid + it * 256;               // 64 k x 16 d-vec4
        int kr = vI >> 4, dc = (vI & 15) * 4;
        float4 f = *reinterpret_cast<const float4*>(&W[(size_t)(k0 + kr) * 64 + dc]);
        Ts[dc + 0][kr] = f2b(f.x);
        Ts[dc + 1][kr] = f2b(f.y);
        Ts[dc + 2][kr] = f2b(f.z);
        Ts[dc + 3][kr] = f2b(f.w);
    }
    __syncthreads();
    #pragma unroll
    for (int it = 0; it < 2; ++it) {
        int vI = tid + it * 256;               // 64 d x 8 k-vec8
        int dr = vI >> 3, kc = (vI & 7) * 8;
        *reinterpret_cast<uint4*>(
            &Wt[((size_t)(m * 1024 + h * 64 + dr)) * 1024 + k0 + kc]) =
            *reinterpret_cast<uint4*>(&Ts[dr][kc]);
    }
}

__global__ __launch_bounds__(256) void biascat_kernel(
    const float* __restrict__ Bq, const float* __restrict__ Bk,
    const float* __restrict__ Bv, float* __restrict__ out)
{
    int i = blockIdx.x * 256 + threadIdx.x;    // 0..3071
    const float* B = (i < 1024 ? Bq : (i < 2048 ? Bk : Bv));
    out[i] = B[i & 1023];
}

// ---------------------------------------------------------------------------
// C = act(A @ Bt^T + bias): A [M,K] bf16, Bt [N,K] bf16.
// 128x128 tile, BK=64, 4 waves 2x2. global_load_lds staging, linear LDS.
// ---------------------------------------------------------------------------
template <int RELU>
__global__ __launch_bounds__(256) void gemm_bt(
    const u16* __restrict__ A, const u16* __restrict__ Bt,
    const float* __restrict__ bias, u16* __restrict__ C,
    int M, int N, int K)
{
    __shared__ __align__(16) u16 As[128 * 64];
    __shared__ __align__(16) u16 Bs[128 * 64];
    const int m0 = blockIdx.x * 128, n0 = blockIdx.y * 128;
    const int tid = threadIdx.x, lane = tid & 63, w = tid >> 6;
    const int wr = w >> 1, wc = w & 1;
    const int g = lane >> 4, ln = lane & 15;
    const int srow = lane >> 3, scol = (lane & 7) * 8;

    f32x4 acc[4][4];
    #pragma unroll
    for (int i = 0; i < 4; ++i)
        #pragma unroll
        for (int j = 0; j < 4; ++j) acc[i][j] = (f32x4){0.f, 0.f, 0.f, 0.f};

    const u16* Abase = A + (size_t)m0 * K;
    const u16* Bbase = Bt + (size_t)n0 * K;

    for (int k0 = 0; k0 < K; k0 += 64) {
        #pragma unroll
        for (int c = 0; c < 4; ++c) {
            int chunk = w * 4 + c;             // 0..15, wave-uniform
            int row = chunk * 8 + srow;
            gload16(&Abase[(size_t)row * K + k0 + scol], (u16*)As + chunk * 512);
            gload16(&Bbase[(size_t)row * K + k0 + scol], (u16*)Bs + chunk * 512);
        }
        __syncthreads();
        #pragma unroll
        for (int kk = 0; kk < 2; ++kk) {
            bf16x8 a[4], b[4];
            #pragma unroll
            for (int i = 0; i < 4; ++i)
                a[i] = *(const bf16x8*)&As[(wr * 64 + i * 16 + ln) * 64 + kk * 32 + g * 8];
            #pragma unroll
            for (int j = 0; j < 4; ++j)
                b[j] = *(const bf16x8*)&Bs[(wc * 64 + j * 16 + ln) * 64 + kk * 32 + g * 8];
            #pragma unroll
            for (int i = 0; i < 4; ++i)
                #pragma unroll
                for (int j = 0; j < 4; ++j)
                    acc[i][j] = MFMA(a[i], b[j], acc[i][j]);
        }
        __syncthreads();
    }

    #pragma unroll
    for (int j = 0; j < 4; ++j) {
        int col = n0 + wc * 64 + j * 16 + ln;
        float bv = bias[col];
        #pragma unroll
        for (int i = 0; i < 4; ++i)
            #pragma unroll
            for (int r = 0; r < 4; ++r) {
                int row = m0 + wr * 64 + i * 16 + g * 4 + r;
                float v = acc[i][j][r] + bv;
                if (RELU) v = fmaxf(v, 0.f);
                C[(size_t)row * N + col] = f2b(v);
            }
    }
}

// ---------------------------------------------------------------------------
// Flash attention over fused qkv buffer [8192, 3072] bf16.
// Q in registers; K/V staged in LDS (V t-index XOR-swizzled by d&56);
// log2-domain online softmax with wave-uniform defer-max; deferred l-reduce.
// ---------------------------------------------------------------------------
__global__ __launch_bounds__(256, 4) void attn_kernel(
    const u16* __restrict__ QKV, u16* __restrict__ O)
{
    const int bh = blockIdx.x, b = bh >> 4, h = bh & 15;
    const int q0 = blockIdx.y * 128;
    const int tid = threadIdx.x;
    const int lane = tid & 63, w = tid >> 6;
    const int g = lane >> 4, ln = lane & 15;

    __shared__ __align__(16) u16 Ks[64][72];
    __shared__ __align__(16) u16 Vts[64][72];
    __shared__ __align__(16) u16 Ps[128][72];

    const u16* Qp = QKV + (size_t)b * 2048 * 3072 + h * 64;
    const u16* Kp = Qp + 1024;
    const u16* Vp = Qp + 2048;

    // Q fragments in registers (loaded once)
    bf16x8 qf[2][2];
    #pragma unroll
    for (int i = 0; i < 2; ++i)
        #pragma unroll
        for (int kk = 0; kk < 2; ++kk)
            qf[i][kk] = *reinterpret_cast<const bf16x8*>(
                &Qp[(size_t)(q0 + w * 32 + i * 16 + ln) * 3072 + kk * 32 + g * 8]);

    f32x4 oacc[2][4];
    float mrun[2][4], lsum[2][4];
    #pragma unroll
    for (int i = 0; i < 2; ++i)
        #pragma unroll
        for (int n = 0; n < 4; ++n) oacc[i][n] = (f32x4){0.f, 0.f, 0.f, 0.f};
    #pragma unroll
    for (int i = 0; i < 2; ++i)
        #pragma unroll
        for (int r = 0; r < 4; ++r) { mrun[i][r] = -1e30f; lsum[i][r] = 0.f; }

    const float C1 = 0.125f * 1.44269504f;     // 1/sqrt(64) * log2(e)

    for (int t0 = 0; t0 < 2048; t0 += 64) {
        __syncthreads();   // prev PV reads done before overwriting Ks/Vts/Ps
        #pragma unroll
        for (int it = 0; it < 2; ++it) {
            int vI = tid + it * 256;
            int row = vI >> 3, col = (vI & 7) * 8;
            *reinterpret_cast<uint4*>(&Ks[row][col]) =
                *reinterpret_cast<const uint4*>(&Kp[(size_t)(t0 + row) * 3072 + col]);
            uint4 t = *reinterpret_cast<const uint4*>(&Vp[(size_t)(t0 + row) * 3072 + col]);
            const u16* tv = reinterpret_cast<const u16*>(&t);
            #pragma unroll
            for (int j = 0; j < 8; ++j) {
                int d = col + j;
                Vts[d][row ^ (d & 56)] = tv[j];   // XOR-swizzle: write 2-way free
            }
        }
        __syncthreads();

        // S = Q K^T
        f32x4 sacc[2][4];
        #pragma unroll
        for (int i = 0; i < 2; ++i)
            #pragma unroll
            for (int j = 0; j < 4; ++j) sacc[i][j] = (f32x4){0.f, 0.f, 0.f, 0.f};
        #pragma unroll
        for (int kk = 0; kk < 2; ++kk) {
            #pragma unroll
            for (int j = 0; j < 4; ++j) {
                bf16x8 bb = *(const bf16x8*)&Ks[j * 16 + ln][kk * 32 + g * 8];
                sacc[0][j] = MFMA(qf[0][kk], bb, sacc[0][j]);
                sacc[1][j] = MFMA(qf[1][kk], bb, sacc[1][j]);
            }
        }

        // --- online softmax, log2 domain ---
        float tl[2][4];
        int small_ = 1;
        #pragma unroll
        for (int i = 0; i < 2; ++i)
            #pragma unroll
            for (int r = 0; r < 4; ++r) {
                float t = fmaxf(fmaxf(sacc[i][0][r], sacc[i][1][r]),
                                fmaxf(sacc[i][2][r], sacc[i][3][r])) * C1;
                tl[i][r] = t;
                small_ &= (t <= mrun[i][r] + 10.f);
            }
        if (!__all(small_)) {
            // rare: row max grew beyond 2^10 headroom -> rescale
            #pragma unroll
            for (int i = 0; i < 2; ++i)
                #pragma unroll
                for (int r = 0; r < 4; ++r) {
                    float t = tl[i][r];
                    #pragma unroll
                    for (int mm = 1; mm < 16; mm <<= 1)
                        t = fmaxf(t, __shfl_xor(t, mm));
                    float mn = fmaxf(mrun[i][r], t);
                    float al = exp2f(mrun[i][r] - mn);
                    mrun[i][r] = mn;
                    lsum[i][r] *= al;
                    #pragma unroll
                    for (int n = 0; n < 4; ++n) oacc[i][n][r] *= al;
                }
        }
        #pragma unroll
        for (int i = 0; i < 2; ++i)
            #pragma unroll
            for (int r = 0; r < 4; ++r) {
                float mm_ = mrun[i][r];
                float ps = 0.f;
                #pragma unroll
                for (int j = 0; j < 4; ++j) {
                    float p = exp2f(fmaf(sacc[i][j][r], C1, -mm_));
                    ps += p;
                    Ps[w * 32 + i * 16 + g * 4 + r][j * 16 + ln] = cvtb(p);
                }
                lsum[i][r] += ps;    // per-lane partial; reduced once at end
            }
        __syncthreads();

        // O += P V
        #pragma unroll
        for (int kk = 0; kk < 2; ++kk) {
            bf16x8 a[2];
            a[0] = *(const bf16x8*)&Ps[w * 32 + ln][kk * 32 + g * 8];
            a[1] = *(const bf16x8*)&Ps[w * 32 + 16 + ln][kk * 32 + g * 8];
            #pragma unroll
            for (int n = 0; n < 4; ++n) {
                int d = n * 16 + ln;
                bf16x8 bb = *(const bf16x8*)&Vts[d][(kk * 32 + g * 8) ^ (d & 56)];
                oacc[0][n] = MFMA(a[0], bb, oacc[0][n]);
                oacc[1][n] = MFMA(a[1], bb, oacc[1][n]);
            }
        }
    }

    #pragma unroll
    for (int i = 0; i < 2; ++i)
        #pragma unroll
        for (int r = 0; r < 4; ++r) {
            float s = lsum[i][r];
            #pragma unroll
            for (int mm = 1; mm < 16; mm <<= 1) s += __shfl_xor(s, mm);
            float rinv = __builtin_amdgcn_rcpf(s);
            int row = q0 + w * 32 + i * 16 + g * 4 + r;
            #pragma unroll
            for (int n = 0; n < 4; ++n)
                O[((size_t)(b * 2048 + row)) * 1024 + h * 64 + n * 16 + ln] =
                    cvtb(oacc[i][n][r] * rinv);
        }
}

// ---------------------------------------------------------------------------
// out[row] = Src[row] + LayerNorm(T[row]) * g + b    (row = 1024 elems)
// ---------------------------------------------------------------------------
template <int SRC_F32, int OUT_F32>
__global__ __launch_bounds__(256) void ln_add_kernel(
    const u16* __restrict__ T, const void* __restrict__ SrcV,
    const float* __restrict__ G, const float* __restrict__ Bt,
    void* __restrict__ OutV)
{
    const int row = blockIdx.x;
    const int tid = threadIdx.x;
    __shared__ float red[8];

    const size_t rb = (size_t)row * 1024;
    ushort4 tv = *reinterpret_cast<const ushort4*>(&T[rb + tid * 4]);
    float v0 = b2f(tv.x), v1 = b2f(tv.y), v2 = b2f(tv.z), v3 = b2f(tv.w);
    float s = v0 + v1 + v2 + v3;
    float sq = v0 * v0 + v1 * v1 + v2 * v2 + v3 * v3;
    #pragma unroll
    for (int mm = 1; mm < 64; mm <<= 1) {
        s += __shfl_xor(s, mm);
        sq += __shfl_xor(sq, mm);
    }
    if ((tid & 63) == 0) { red[tid >> 6] = s; red[4 + (tid >> 6)] = sq; }
    __syncthreads();
    s = red[0] + red[1] + red[2] + red[3];
    sq = red[4] + red[5] + red[6] + red[7];
    float mu = s * (1.f / 1024.f);
    float var = sq * (1.f / 1024.f) - mu * mu;
    float rs = rsqrtf(var + 1e-5f);

    float s0, s1, s2, s3;
    if (SRC_F32) {
        float4 sv = *reinterpret_cast<const float4*>((const float*)SrcV + rb + tid * 4);
        s0 = sv.x; s1 = sv.y; s2 = sv.z; s3 = sv.w;
    } else {
        ushort4 sv = *reinterpret_cast<const ushort4*>((const u16*)SrcV + rb + tid * 4);
        s0 = b2f(sv.x); s1 = b2f(sv.y); s2 = b2f(sv.z); s3 = b2f(sv.w);
    }
    float4 gv = *reinterpret_cast<const float4*>(&G[tid * 4]);
    float4 bv = *reinterpret_cast<const float4*>(&Bt[tid * 4]);
    float o0 = s0 + (v0 - mu) * rs * gv.x + bv.x;
    float o1 = s1 + (v1 - mu) * rs * gv.y + bv.y;
    float o2 = s2 + (v2 - mu) * rs * gv.z + bv.z;
    float o3 = s3 + (v3 - mu) * rs * gv.w + bv.w;
    if (OUT_F32) {
        float4 ov = {o0, o1, o2, o3};
        *reinterpret_cast<float4*>((float*)OutV + rb + tid * 4) = ov;
    } else {
        ushort4 ov = {f2b(o0), f2b(o1), f2b(o2), f2b(o3)};
        *reinterpret_cast<ushort4*>((u16*)OutV + rb + tid * 4) = ov;
    }
}

// ---------------------------------------------------------------------------
extern "C" void kernel_launch(void* const* d_in, const int* in_sizes, int n_in,
                              void* d_out, int out_size, void* d_ws, size_t ws_size,
                              hipStream_t stream)
{
    const float* X   = (const float*)d_in[0];
    const float* Wq  = (const float*)d_in[1];
    const float* Bq  = (const float*)d_in[2];
    const float* Wk  = (const float*)d_in[3];
    const float* Bk  = (const float*)d_in[4];
    const float* Wv  = (const float*)d_in[5];
    const float* Bv  = (const float*)d_in[6];
    const float* g1  = (const float*)d_in[7];
    const float* b1  = (const float*)d_in[8];
    const float* W1  = (const float*)d_in[9];
    const float* B1  = (const float*)d_in[10];
    const float* W2  = (const float*)d_in[11];
    const float* B2  = (const float*)d_in[12];
    const float* g2  = (const float*)d_in[13];
    const float* b2  = (const float*)d_in[14];
    float* out = (float*)d_out;

    char* ws = (char*)d_ws;
    const size_t MiB = 1048576;
    u16*   qkv   = (u16*)(ws);              // [8192,3072] 48MiB; dead after attn
    u16*   hid   = (u16*)(ws);              // [4096,4096] 32MiB chunk; after attn
    u16*   ff    = (u16*)(ws + 32 * MiB);   // [8192,1024] 16MiB; after attn
    u16*   Xb    = (u16*)(ws + 48 * MiB);   // 16MiB; dead after qkv gemm
    u16*   attnb = (u16*)(ws + 48 * MiB);   // 16MiB; written after Xb dead
    u16*   wqkvt = (u16*)(ws + 64 * MiB);   // [3072,1024] 6MiB; dead after qkv gemm
    float* bcat  = (float*)(ws + 70 * MiB); // 12KiB; dead after qkv gemm
    u16*   res1  = (u16*)(ws + 64 * MiB);   // 16MiB; written by ln1 (wqkvt dead)
    u16*   w1t   = (u16*)(ws + 80 * MiB);   // [4096,1024] 8MiB
    u16*   w2t   = (u16*)(ws + 88 * MiB);   // [1024,4096] 8MiB

    xcvt_kernel<<<4096, 256, 0, stream>>>(X, Xb);
    wT_kernel<<<dim3(16, 64), 256, 0, stream>>>(W1, w1t, 1024, 4096);
    wT_kernel<<<dim3(64, 16), 256, 0, stream>>>(W2, w2t, 4096, 1024);
    wqkvT_kernel<<<dim3(16, 16, 3), 256, 0, stream>>>(Wq, Wk, Wv, wqkvt);
    biascat_kernel<<<12, 256, 0, stream>>>(Bq, Bk, Bv, bcat);

    gemm_bt<0><<<dim3(64, 24), 256, 0, stream>>>(Xb, wqkvt, bcat, qkv, 8192, 3072, 1024);
    attn_kernel<<<dim3(64, 16), 256, 0, stream>>>(qkv, attnb);
    ln_add_kernel<1, 0><<<8192, 256, 0, stream>>>(attnb, X, g1, b1, res1);

    for (int c = 0; c < 2; ++c) {
        const u16* a1 = res1 + (size_t)c * 4096 * 1024;
        u16* f1 = ff + (size_t)c * 4096 * 1024;
        gemm_bt<1><<<dim3(32, 32), 256, 0, stream>>>(a1, w1t, B1, hid, 4096, 4096, 1024);
        gemm_bt<0><<<dim3(32, 8), 256, 0, stream>>>(hid, w2t, B2, f1, 4096, 1024, 4096);
    }
    ln_add_kernel<0, 1><<<8192, 256, 0, stream>>>(ff, res1, g2, b2, out);
}

// Round 5
// 531.484 us; speedup vs baseline: 2.1880x; 1.0344x over previous
//
#include <hip/hip_runtime.h>
#include <cstdint>
#include <cmath>

typedef unsigned short u16;
using bf16x8 = __attribute__((ext_vector_type(8))) __bf16;
using f32x4  = __attribute__((ext_vector_type(4))) float;

#define MFMA(a, b, c) __builtin_amdgcn_mfma_f32_16x16x32_bf16((a), (b), (c), 0, 0, 0)

__device__ __forceinline__ float b2f(u16 u) {
    union { unsigned int i; float f; } x; x.i = ((unsigned int)u) << 16; return x.f;
}
__device__ __forceinline__ u16 f2b(float f) {
    union { float f; unsigned int i; } x; x.f = f;
    unsigned int r = x.i + 0x7FFFu + ((x.i >> 16) & 1u);
    return (u16)(r >> 16);
}
__device__ __forceinline__ u16 cvtb(float f) {
    __bf16 h = (__bf16)f;
    return *reinterpret_cast<u16*>(&h);
}
__device__ __forceinline__ uint32_t cvtpk(float lo, float hi) {  // 2xbf16 packed
    uint32_t r;
    asm("v_cvt_pk_bf16_f32 %0, %1, %2" : "=v"(r) : "v"(lo), "v"(hi));
    return r;
}

// async global -> LDS, 16B per lane. LDS dest = wave-uniform base + lane*16.
__device__ __forceinline__ void gload16(const u16* g, u16* l) {
    __builtin_amdgcn_global_load_lds(
        (const __attribute__((address_space(1))) void*)g,
        (__attribute__((address_space(3))) void*)l, 16, 0, 0);
}

// ---------------------------------------------------------------------------
// X fp32 -> bf16 (contiguous, 8 elems/thread)
// ---------------------------------------------------------------------------
__global__ __launch_bounds__(256) void xcvt_kernel(const float* __restrict__ X,
                                                   u16* __restrict__ Xb)
{
    size_t i = ((size_t)blockIdx.x * 256 + threadIdx.x) * 8;
    float4 a = *reinterpret_cast<const float4*>(&X[i]);
    float4 b = *reinterpret_cast<const float4*>(&X[i + 4]);
    ushort4 lo = {f2b(a.x), f2b(a.y), f2b(a.z), f2b(a.w)};
    ushort4 hi = {f2b(b.x), f2b(b.y), f2b(b.z), f2b(b.w)};
    *reinterpret_cast<ushort4*>(&Xb[i]) = lo;
    *reinterpret_cast<ushort4*>(&Xb[i + 4]) = hi;
}

// ---------------------------------------------------------------------------
// W [K,N] fp32 -> Wt [N,K] bf16   (64x64 tiles via LDS)
// ---------------------------------------------------------------------------
__global__ __launch_bounds__(256) void wT_kernel(const float* __restrict__ W,
                                                 u16* __restrict__ Wt, int K, int N)
{
    __shared__ __align__(16) u16 Ts[64][72];
    const int k0 = blockIdx.x * 64, n0 = blockIdx.y * 64;
    const int tid = threadIdx.x;
    #pragma unroll
    for (int it = 0; it < 4; ++it) {
        int vI = tid + it * 256;               // 64 k x 16 n-vec4
        int kr = vI >> 4, nc = (vI & 15) * 4;
        float4 f = *reinterpret_cast<const float4*>(&W[(size_t)(k0 + kr) * N + n0 + nc]);
        Ts[nc + 0][kr] = f2b(f.x);
        Ts[nc + 1][kr] = f2b(f.y);
        Ts[nc + 2][kr] = f2b(f.z);
        Ts[nc + 3][kr] = f2b(f.w);
    }
    __syncthreads();
    #pragma unroll
    for (int it = 0; it < 2; ++it) {
        int vI = tid + it * 256;               // 64 n x 8 k-vec8
        int nr = vI >> 3, kc = (vI & 7) * 8;
        *reinterpret_cast<uint4*>(&Wt[(size_t)(n0 + nr) * K + k0 + kc]) =
            *reinterpret_cast<uint4*>(&Ts[nr][kc]);
    }
}

// ---------------------------------------------------------------------------
// Wq/Wk/Wv [16,1024,64] fp32 -> Wcat_t [3072,1024] bf16, row = m*1024+h*64+d
// ---------------------------------------------------------------------------
__global__ __launch_bounds__(256) void wqkvT_kernel(
    const float* __restrict__ Wq, const float* __restrict__ Wk,
    const float* __restrict__ Wv, u16* __restrict__ Wt)
{
    __shared__ __align__(16) u16 Ts[64][72];
    const int k0 = blockIdx.x * 64, h = blockIdx.y, m = blockIdx.z;
    const float* W = (m == 0 ? Wq : (m == 1 ? Wk : Wv)) + (size_t)h * 65536;
    const int tid = threadIdx.x;
    #pragma unroll
    for (int it = 0; it < 4; ++it) {
        int vI = tid + it * 256;               // 64 k x 16 d-vec4
        int kr = vI >> 4, dc = (vI & 15) * 4;
        float4 f = *reinterpret_cast<const float4*>(&W[(size_t)(k0 + kr) * 64 + dc]);
        Ts[dc + 0][kr] = f2b(f.x);
        Ts[dc + 1][kr] = f2b(f.y);
        Ts[dc + 2][kr] = f2b(f.z);
        Ts[dc + 3][kr] = f2b(f.w);
    }
    __syncthreads();
    #pragma unroll
    for (int it = 0; it < 2; ++it) {
        int vI = tid + it * 256;               // 64 d x 8 k-vec8
        int dr = vI >> 3, kc = (vI & 7) * 8;
        *reinterpret_cast<uint4*>(
            &Wt[((size_t)(m * 1024 + h * 64 + dr)) * 1024 + k0 + kc]) =
            *reinterpret_cast<uint4*>(&Ts[dr][kc]);
    }
}

__global__ __launch_bounds__(256) void biascat_kernel(
    const float* __restrict__ Bq, const float* __restrict__ Bk,
    const float* __restrict__ Bv, float* __restrict__ out)
{
    int i = blockIdx.x * 256 + threadIdx.x;    // 0..3071
    const float* B = (i < 1024 ? Bq : (i < 2048 ? Bk : Bv));
    out[i] = B[i & 1023];
}

// ---------------------------------------------------------------------------
// C = act(A @ Bt^T + bias): A [M,K] bf16, Bt [N,K] bf16.
// 128x128 tile, BK=64, 4 waves 2x2. global_load_lds staging, linear LDS.
// ---------------------------------------------------------------------------
template <int RELU>
__global__ __launch_bounds__(256) void gemm_bt(
    const u16* __restrict__ A, const u16* __restrict__ Bt,
    const float* __restrict__ bias, u16* __restrict__ C,
    int M, int N, int K)
{
    __shared__ __align__(16) u16 As[128 * 64];
    __shared__ __align__(16) u16 Bs[128 * 64];
    const int m0 = blockIdx.x * 128, n0 = blockIdx.y * 128;
    const int tid = threadIdx.x, lane = tid & 63, w = tid >> 6;
    const int wr = w >> 1, wc = w & 1;
    const int g = lane >> 4, ln = lane & 15;
    const int srow = lane >> 3, scol = (lane & 7) * 8;

    f32x4 acc[4][4];
    #pragma unroll
    for (int i = 0; i < 4; ++i)
        #pragma unroll
        for (int j = 0; j < 4; ++j) acc[i][j] = (f32x4){0.f, 0.f, 0.f, 0.f};

    const u16* Abase = A + (size_t)m0 * K;
    const u16* Bbase = Bt + (size_t)n0 * K;

    for (int k0 = 0; k0 < K; k0 += 64) {
        #pragma unroll
        for (int c = 0; c < 4; ++c) {
            int chunk = w * 4 + c;             // 0..15, wave-uniform
            int row = chunk * 8 + srow;
            gload16(&Abase[(size_t)row * K + k0 + scol], (u16*)As + chunk * 512);
            gload16(&Bbase[(size_t)row * K + k0 + scol], (u16*)Bs + chunk * 512);
        }
        __syncthreads();
        #pragma unroll
        for (int kk = 0; kk < 2; ++kk) {
            bf16x8 a[4], b[4];
            #pragma unroll
            for (int i = 0; i < 4; ++i)
                a[i] = *(const bf16x8*)&As[(wr * 64 + i * 16 + ln) * 64 + kk * 32 + g * 8];
            #pragma unroll
            for (int j = 0; j < 4; ++j)
                b[j] = *(const bf16x8*)&Bs[(wc * 64 + j * 16 + ln) * 64 + kk * 32 + g * 8];
            #pragma unroll
            for (int i = 0; i < 4; ++i)
                #pragma unroll
                for (int j = 0; j < 4; ++j)
                    acc[i][j] = MFMA(a[i], b[j], acc[i][j]);
        }
        __syncthreads();
    }

    #pragma unroll
    for (int j = 0; j < 4; ++j) {
        int col = n0 + wc * 64 + j * 16 + ln;
        float bv = bias[col];
        #pragma unroll
        for (int i = 0; i < 4; ++i)
            #pragma unroll
            for (int r = 0; r < 4; ++r) {
                int row = m0 + wr * 64 + i * 16 + g * 4 + r;
                float v = acc[i][j][r] + bv;
                if (RELU) v = fmaxf(v, 0.f);
                C[(size_t)row * N + col] = f2b(v);
            }
    }
}

// ---------------------------------------------------------------------------
// Flash attention, fused qkv buffer [8192,3072] bf16.
// Swapped QK^T (D=S^T) -> softmax fully in-register -> PV with a custom
// (g,c)->t k-slot bijection matching the lane-local P layout (no P in LDS).
// V staged with the matching bit-permuted slot index s(t)=[t5 t3 t2 t4 t1 t0],
// XOR d&56 swizzle on top. 2 barriers/tile. LDS = 18.4KB.
// ---------------------------------------------------------------------------
__global__ __launch_bounds__(256, 3) void attn_kernel(
    const u16* __restrict__ QKV, u16* __restrict__ O)
{
    const int bh = blockIdx.x, b = bh >> 4, h = bh & 15;
    const int q0 = blockIdx.y * 128;
    const int tid = threadIdx.x;
    const int lane = tid & 63, w = tid >> 6;
    const int g = lane >> 4, ln = lane & 15;

    __shared__ __align__(16) u16 Ks[64][72];
    __shared__ __align__(16) u16 Vt2[64][72];

    const u16* Qp = QKV + (size_t)b * 2048 * 3072 + h * 64;
    const u16* Kp = Qp + 1024;
    const u16* Vp = Qp + 2048;

    // Q fragments in registers (loaded once); lane holds Q[q=i*16+ln][32kk+8g+c]
    bf16x8 qf[2][2];
    #pragma unroll
    for (int i = 0; i < 2; ++i)
        #pragma unroll
        for (int kk = 0; kk < 2; ++kk)
            qf[i][kk] = *reinterpret_cast<const bf16x8*>(
                &Qp[(size_t)(q0 + w * 32 + i * 16 + ln) * 3072 + kk * 32 + g * 8]);

    f32x4 oacc[2][4];
    #pragma unroll
    for (int i = 0; i < 2; ++i)
        #pragma unroll
        for (int n = 0; n < 4; ++n) oacc[i][n] = (f32x4){0.f, 0.f, 0.f, 0.f};
    float mrun[2] = {-1e30f, -1e30f};   // per-lane row q = i*16+ln (g-uniform)
    float lsum[2] = {0.f, 0.f};         // per-lane partial over this lane's t-set

    const float C1 = 0.125f * 1.44269504f;   // 1/sqrt(64) * log2(e)

    for (int t0 = 0; t0 < 2048; t0 += 64) {
        __syncthreads();   // prev tile's QK/PV reads done before restaging
        #pragma unroll
        for (int it = 0; it < 2; ++it) {
            int vI = tid + it * 256;
            int row = vI >> 3, col = (vI & 7) * 8;
            *reinterpret_cast<uint4*>(&Ks[row][col]) =
                *reinterpret_cast<const uint4*>(&Kp[(size_t)(t0 + row) * 3072 + col]);
            uint4 t = *reinterpret_cast<const uint4*>(&Vp[(size_t)(t0 + row) * 3072 + col]);
            const u16* tv = reinterpret_cast<const u16*>(&t);
            // slot s(t): bits [t5 t3 t2 t4 t1 t0] (bijective)
            int s = (row & 32) | ((row & 12) << 1) | ((row & 16) >> 2) | (row & 3);
            #pragma unroll
            for (int j = 0; j < 8; ++j) {
                int d = col + j;
                Vt2[d][s ^ (d & 56)] = tv[j];
            }
        }
        __syncthreads();

        // S^T = mfma(K, Q): lane holds S[q=i*16+ln][t=16j+4g+r]
        f32x4 sc[4][2];
        #pragma unroll
        for (int j = 0; j < 4; ++j)
            #pragma unroll
            for (int i = 0; i < 2; ++i) sc[j][i] = (f32x4){0.f, 0.f, 0.f, 0.f};
        #pragma unroll
        for (int kk = 0; kk < 2; ++kk)
            #pragma unroll
            for (int j = 0; j < 4; ++j) {
                bf16x8 kb = *(const bf16x8*)&Ks[j * 16 + ln][kk * 32 + g * 8];
                sc[j][0] = MFMA(kb, qf[0][kk], sc[j][0]);
                sc[j][1] = MFMA(kb, qf[1][kk], sc[j][1]);
            }

        // ---- in-register online softmax (log2 domain, defer-max) ----
        float tl[2];
        #pragma unroll
        for (int i = 0; i < 2; ++i) {
            float t01 = fmaxf(fmaxf(sc[0][i][0], sc[0][i][1]),
                              fmaxf(sc[0][i][2], sc[0][i][3]));
            float t23 = fmaxf(fmaxf(sc[1][i][0], sc[1][i][1]),
                              fmaxf(sc[1][i][2], sc[1][i][3]));
            float t45 = fmaxf(fmaxf(sc[2][i][0], sc[2][i][1]),
                              fmaxf(sc[2][i][2], sc[2][i][3]));
            float t67 = fmaxf(fmaxf(sc[3][i][0], sc[3][i][1]),
                              fmaxf(sc[3][i][2], sc[3][i][3]));
            tl[i] = fmaxf(fmaxf(t01, t23), fmaxf(t45, t67)) * C1;
        }
        int small_ = (tl[0] <= mrun[0] + 10.f) && (tl[1] <= mrun[1] + 10.f);
        if (!__all(small_)) {
            #pragma unroll
            for (int i = 0; i < 2; ++i) {
                float t = tl[i];
                t = fmaxf(t, __shfl_xor(t, 16));
                t = fmaxf(t, __shfl_xor(t, 32));   // row max (g-reduce)
                float mn = fmaxf(mrun[i], t);
                float al = exp2f(mrun[i] - mn);
                mrun[i] = mn;
                lsum[i] *= al;
                // oacc rows are q=i*16+g*4+r; al lives at q=i*16+ln -> shfl
                #pragma unroll
                for (int r = 0; r < 4; ++r) {
                    float alr = __shfl(al, g * 4 + r);
                    #pragma unroll
                    for (int n = 0; n < 4; ++n) oacc[i][n][r] *= alr;
                }
            }
        }
        // P = exp2(S*C1 - m), packed to bf16 pairs in-lane
        uint32_t pk[2][8];
        #pragma unroll
        for (int i = 0; i < 2; ++i) {
            float m_ = mrun[i];
            float ps = 0.f;
            #pragma unroll
            for (int j = 0; j < 4; ++j) {
                #pragma unroll
                for (int r = 0; r < 4; ++r) {
                    float p = exp2f(fmaf(sc[j][i][r], C1, -m_));
                    sc[j][i][r] = p;
                    ps += p;
                }
                pk[i][j * 2 + 0] = cvtpk(sc[j][i][0], sc[j][i][1]);
                pk[i][j * 2 + 1] = cvtpk(sc[j][i][2], sc[j][i][3]);
            }
            lsum[i] += ps;
        }

        // PV: k-slot (g,c) -> t = 16*(2kk+(c>>2)) + 4g + (c&3); A=P in-lane,
        // B=V^T from Vt2 (stored with matching s(t) permutation).
        #pragma unroll
        for (int kk = 0; kk < 2; ++kk) {
            union { uint32_t u[4]; bf16x8 v; } af0, af1;
            af0.u[0] = pk[0][kk * 4 + 0]; af0.u[1] = pk[0][kk * 4 + 1];
            af0.u[2] = pk[0][kk * 4 + 2]; af0.u[3] = pk[0][kk * 4 + 3];
            af1.u[0] = pk[1][kk * 4 + 0]; af1.u[1] = pk[1][kk * 4 + 1];
            af1.u[2] = pk[1][kk * 4 + 2]; af1.u[3] = pk[1][kk * 4 + 3];
            #pragma unroll
            for (int n = 0; n < 4; ++n) {
                int d = n * 16 + ln;
                bf16x8 vb = *(const bf16x8*)&Vt2[d][(kk * 32 + g * 8) ^ (d & 56)];
                oacc[0][n] = MFMA(af0.v, vb, oacc[0][n]);
                oacc[1][n] = MFMA(af1.v, vb, oacc[1][n]);
            }
        }
    }

    // epilogue: complete row sums (g-reduce), redistribute to oacc row layout
    #pragma unroll
    for (int i = 0; i < 2; ++i) {
        float s = lsum[i];
        s += __shfl_xor(s, 16);
        s += __shfl_xor(s, 32);                  // total for q=i*16+ln
        float rinv = __builtin_amdgcn_rcpf(s);
        #pragma unroll
        for (int r = 0; r < 4; ++r) {
            float rv = __shfl(rinv, g * 4 + r);  // q=i*16+g*4+r from lane g*4+r
            int row = q0 + w * 32 + i * 16 + g * 4 + r;
            #pragma unroll
            for (int n = 0; n < 4; ++n)
                O[((size_t)(b * 2048 + row)) * 1024 + h * 64 + n * 16 + ln] =
                    cvtb(oacc[i][n][r] * rv);
        }
    }
}

// ---------------------------------------------------------------------------
// out[row] = Src[row] + LayerNorm(T[row]) * g + b    (row = 1024 elems)
// ---------------------------------------------------------------------------
template <int SRC_F32, int OUT_F32>
__global__ __launch_bounds__(256) void ln_add_kernel(
    const u16* __restrict__ T, const void* __restrict__ SrcV,
    const float* __restrict__ G, const float* __restrict__ Bt,
    void* __restrict__ OutV)
{
    const int row = blockIdx.x;
    const int tid = threadIdx.x;
    __shared__ float red[8];

    const size_t rb = (size_t)row * 1024;
    ushort4 tv = *reinterpret_cast<const ushort4*>(&T[rb + tid * 4]);
    float v0 = b2f(tv.x), v1 = b2f(tv.y), v2 = b2f(tv.z), v3 = b2f(tv.w);
    float s = v0 + v1 + v2 + v3;
    float sq = v0 * v0 + v1 * v1 + v2 * v2 + v3 * v3;
    #pragma unroll
    for (int mm = 1; mm < 64; mm <<= 1) {
        s += __shfl_xor(s, mm);
        sq += __shfl_xor(sq, mm);
    }
    if ((tid & 63) == 0) { red[tid >> 6] = s; red[4 + (tid >> 6)] = sq; }
    __syncthreads();
    s = red[0] + red[1] + red[2] + red[3];
    sq = red[4] + red[5] + red[6] + red[7];
    float mu = s * (1.f / 1024.f);
    float var = sq * (1.f / 1024.f) - mu * mu;
    float rs = rsqrtf(var + 1e-5f);

    float s0, s1, s2, s3;
    if (SRC_F32) {
        float4 sv = *reinterpret_cast<const float4*>((const float*)SrcV + rb + tid * 4);
        s0 = sv.x; s1 = sv.y; s2 = sv.z; s3 = sv.w;
    } else {
        ushort4 sv = *reinterpret_cast<const ushort4*>((const u16*)SrcV + rb + tid * 4);
        s0 = b2f(sv.x); s1 = b2f(sv.y); s2 = b2f(sv.z); s3 = b2f(sv.w);
    }
    float4 gv = *reinterpret_cast<const float4*>(&G[tid * 4]);
    float4 bv = *reinterpret_cast<const float4*>(&Bt[tid * 4]);
    float o0 = s0 + (v0 - mu) * rs * gv.x + bv.x;
    float o1 = s1 + (v1 - mu) * rs * gv.y + bv.y;
    float o2 = s2 + (v2 - mu) * rs * gv.z + bv.z;
    float o3 = s3 + (v3 - mu) * rs * gv.w + bv.w;
    if (OUT_F32) {
        float4 ov = {o0, o1, o2, o3};
        *reinterpret_cast<float4*>((float*)OutV + rb + tid * 4) = ov;
    } else {
        ushort4 ov = {f2b(o0), f2b(o1), f2b(o2), f2b(o3)};
        *reinterpret_cast<ushort4*>((u16*)OutV + rb + tid * 4) = ov;
    }
}

// ---------------------------------------------------------------------------
extern "C" void kernel_launch(void* const* d_in, const int* in_sizes, int n_in,
                              void* d_out, int out_size, void* d_ws, size_t ws_size,
                              hipStream_t stream)
{
    const float* X   = (const float*)d_in[0];
    const float* Wq  = (const float*)d_in[1];
    const float* Bq  = (const float*)d_in[2];
    const float* Wk  = (const float*)d_in[3];
    const float* Bk  = (const float*)d_in[4];
    const float* Wv  = (const float*)d_in[5];
    const float* Bv  = (const float*)d_in[6];
    const float* g1  = (const float*)d_in[7];
    const float* b1  = (const float*)d_in[8];
    const float* W1  = (const float*)d_in[9];
    const float* B1  = (const float*)d_in[10];
    const float* W2  = (const float*)d_in[11];
    const float* B2  = (const float*)d_in[12];
    const float* g2  = (const float*)d_in[13];
    const float* b2  = (const float*)d_in[14];
    float* out = (float*)d_out;

    char* ws = (char*)d_ws;
    const size_t MiB = 1048576;
    u16*   qkv   = (u16*)(ws);              // [8192,3072] 48MiB; dead after attn
    u16*   hid   = (u16*)(ws);              // [4096,4096] 32MiB chunk; after attn
    u16*   ff    = (u16*)(ws + 32 * MiB);   // [8192,1024] 16MiB; after attn
    u16*   Xb    = (u16*)(ws + 48 * MiB);   // 16MiB; dead after qkv gemm
    u16*   attnb = (u16*)(ws + 48 * MiB);   // 16MiB; written after Xb dead
    u16*   wqkvt = (u16*)(ws + 64 * MiB);   // [3072,1024] 6MiB; dead after qkv gemm
    float* bcat  = (float*)(ws + 70 * MiB); // 12KiB; dead after qkv gemm
    u16*   res1  = (u16*)(ws + 64 * MiB);   // 16MiB; written by ln1 (wqkvt dead)
    u16*   w1t   = (u16*)(ws + 80 * MiB);   // [4096,1024] 8MiB
    u16*   w2t   = (u16*)(ws + 88 * MiB);   // [1024,4096] 8MiB

    xcvt_kernel<<<4096, 256, 0, stream>>>(X, Xb);
    wT_kernel<<<dim3(16, 64), 256, 0, stream>>>(W1, w1t, 1024, 4096);
    wT_kernel<<<dim3(64, 16), 256, 0, stream>>>(W2, w2t, 4096, 1024);
    wqkvT_kernel<<<dim3(16, 16, 3), 256, 0, stream>>>(Wq, Wk, Wv, wqkvt);
    biascat_kernel<<<12, 256, 0, stream>>>(Bq, Bk, Bv, bcat);

    gemm_bt<0><<<dim3(64, 24), 256, 0, stream>>>(Xb, wqkvt, bcat, qkv, 8192, 3072, 1024);
    attn_kernel<<<dim3(64, 16), 256, 0, stream>>>(qkv, attnb);
    ln_add_kernel<1, 0><<<8192, 256, 0, stream>>>(attnb, X, g1, b1, res1);

    for (int c = 0; c < 2; ++c) {
        const u16* a1 = res1 + (size_t)c * 4096 * 1024;
        u16* f1 = ff + (size_t)c * 4096 * 1024;
        gemm_bt<1><<<dim3(32, 32), 256, 0, stream>>>(a1, w1t, B1, hid, 4096, 4096, 1024);
        gemm_bt<0><<<dim3(32, 8), 256, 0, stream>>>(hid, w2t, B2, f1, 4096, 1024, 4096);
    }
    ln_add_kernel<0, 1><<<8192, 256, 0, stream>>>(ff, res1, g2, b2, out);
}